// Round 4
// baseline (2769.032 us; speedup 1.0000x reference)
//
#include <hip/hip_runtime.h>
#include <hip/hip_bf16.h>

#define FEAT 256
#define HID 128
#define CLASSES 32
#define LAYERS 3

typedef float f4 __attribute__((ext_vector_type(4)));
typedef float f2 __attribute__((ext_vector_type(2)));

// ---------------- CSR build ----------------

__global__ void count_kernel(const int* __restrict__ dst, int* __restrict__ counts, int E) {
    int e = blockIdx.x * blockDim.x + threadIdx.x;
    if (e < E) atomicAdd(&counts[dst[e]], 1);
}

// per-256-chunk sums
__global__ void partial_kernel(const int* __restrict__ counts, int* __restrict__ partials, int N) {
    int t = threadIdx.x;
    int i = blockIdx.x * 256 + t;
    int v = (i < N) ? counts[i] : 0;
#pragma unroll
    for (int off = 32; off >= 1; off >>= 1) v += __shfl_down(v, off, 64);
    __shared__ int ws[4];
    if ((t & 63) == 0) ws[t >> 6] = v;
    __syncthreads();
    if (t == 0) partials[blockIdx.x] = ws[0] + ws[1] + ws[2] + ws[3];
}

// exclusive scan of partials (NB <= 256), one block
__global__ void scan_partials_kernel(const int* __restrict__ partials, int* __restrict__ poff, int NB) {
    int t = threadIdx.x, lane = t & 63, w = t >> 6;
    int v = (t < NB) ? partials[t] : 0;
    int x = v;
#pragma unroll
    for (int off = 1; off < 64; off <<= 1) {
        int y = __shfl_up(x, off, 64);
        if (lane >= off) x += y;
    }
    __shared__ int ws[4];
    if (lane == 63) ws[w] = x;
    __syncthreads();
    int woff = 0;
    for (int k = 0; k < w; ++k) woff += ws[k];
    if (t < NB) poff[t] = woff + x - v;
}

// final: exclusive scan within chunk + chunk offset
__global__ void scan_final_kernel(const int* __restrict__ counts, const int* __restrict__ poff,
                                  int* __restrict__ row_off, int* __restrict__ cursor, int N) {
    int t = threadIdx.x, lane = t & 63, w = t >> 6;
    int i = blockIdx.x * 256 + t;
    int v = (i < N) ? counts[i] : 0;
    int x = v;
#pragma unroll
    for (int off = 1; off < 64; off <<= 1) {
        int y = __shfl_up(x, off, 64);
        if (lane >= off) x += y;
    }
    __shared__ int ws[4];
    if (lane == 63) ws[w] = x;
    __syncthreads();
    int woff = 0;
    for (int k = 0; k < w; ++k) woff += ws[k];
    int excl = poff[blockIdx.x] + woff + x - v;
    if (i < N) {
        row_off[i] = excl;
        cursor[i] = excl;
        if (i == N - 1) row_off[N] = excl + v;
    }
}

__global__ void fill_kernel(const int* __restrict__ src, const int* __restrict__ dst,
                            int* __restrict__ cursor, int* __restrict__ csr_src, int E) {
    int e = blockIdx.x * blockDim.x + threadIdx.x;
    if (e < E) {
        int pos = atomicAdd(&cursor[dst[e]], 1);
        csr_src[pos] = src[e];
    }
}

// ---------------- tiled fp32 GEMM, 8x8 (or 8x4) per thread ----------------
// out[M x BN] = act( concatK(A0|A1)[M x KTOT] @ concatK(W0;W1)[KTOT x BN] + bias )
// Thread covers rows {r0..r0+3, r0+64..r0+67}, cols {c0..c0+3 (, c0+64..c0+67 if BN==128)}.
template <int BN, int KTOT, bool RELU>
__global__ __launch_bounds__(256, 4) void gemm_kernel(
    const float* __restrict__ A0, int lda0,
    const float* __restrict__ A1, int lda1,
    const float* __restrict__ W0, const float* __restrict__ W1, int K0,
    const float* __restrict__ bias, float* __restrict__ out, int M) {
    constexpr int BM = 128;
    constexpr int KC = 16;
    constexpr int BMP = BM + 2;            // A pitch (floats); <=2-way bank aliasing
    constexpr int TN = (BN == 128) ? 8 : 4;
    constexpr int WF4 = (KC * BN) / 1024;  // f4 loads per thread for W chunk
    constexpr int AF4 = (KC * BM) / 1024;  // f4 loads per thread for A chunk
    constexpr int NCHUNK = KTOT / KC;

    __shared__ float Wl[2][KC][BN];
    __shared__ float Al[2][KC][BMP];

    int t = threadIdx.x;
    int row_base = blockIdx.x * BM;
    int tc = t & 15;
    int tr = t >> 4;
    int c0 = tc * 4;
    int r0 = tr * 4;

    f4 wreg[WF4], areg[AF4];

    auto load_chunk = [&](int kc) {
        int k0 = kc * KC;
        bool second = (k0 >= K0);
#pragma unroll
        for (int i = 0; i < WF4; ++i) {
            int idx = i * 256 + t;
            int kk = idx / (BN / 4);
            int n4 = idx % (BN / 4);
            int k = k0 + kk;
            const float* p = second ? (W1 + (size_t)(k - K0) * BN + n4 * 4)
                                    : (W0 + (size_t)k * BN + n4 * 4);
            wreg[i] = *(const f4*)p;
        }
#pragma unroll
        for (int i = 0; i < AF4; ++i) {
            int idx = i * 256 + t;
            int row = idx >> 2;
            int kq = idx & 3;
            int row_g = row_base + row;
            if (row_g < M) {
                const float* p = second ? (A1 + (size_t)row_g * lda1 + (k0 - K0) + kq * 4)
                                        : (A0 + (size_t)row_g * lda0 + k0 + kq * 4);
                areg[i] = *(const f4*)p;
            } else {
                areg[i] = (f4)0.f;
            }
        }
    };
    auto store_chunk = [&](int buf) {
#pragma unroll
        for (int i = 0; i < WF4; ++i) {
            int idx = i * 256 + t;
            int kk = idx / (BN / 4);
            int n4 = idx % (BN / 4);
            *(f4*)&Wl[buf][kk][n4 * 4] = wreg[i];
        }
#pragma unroll
        for (int i = 0; i < AF4; ++i) {
            int idx = i * 256 + t;
            int row = idx >> 2;
            int kq = idx & 3;
#pragma unroll
            for (int j = 0; j < 4; ++j) Al[buf][kq * 4 + j][row] = areg[i][j];
        }
    };

    float acc[8][TN] = {{0.f}};
    load_chunk(0);
    store_chunk(0);
    __syncthreads();
    for (int kc = 0; kc < NCHUNK; ++kc) {
        int cur = kc & 1;
        if (kc + 1 < NCHUNK) load_chunk(kc + 1);
#pragma unroll
        for (int k = 0; k < KC; ++k) {
            f4 av1 = *(const f4*)&Al[cur][k][r0];
            f4 av2 = *(const f4*)&Al[cur][k][r0 + 64];
            f4 wv1 = *(const f4*)&Wl[cur][k][c0];
            float ar[8] = {av1[0], av1[1], av1[2], av1[3], av2[0], av2[1], av2[2], av2[3]};
            if (BN == 128) {
                f4 wv2 = *(const f4*)&Wl[cur][k][c0 + 64];
#pragma unroll
                for (int ii = 0; ii < 8; ++ii) {
#pragma unroll
                    for (int jj = 0; jj < 4; ++jj) {
                        acc[ii][jj] = fmaf(ar[ii], wv1[jj], acc[ii][jj]);
                        acc[ii][jj + 4] = fmaf(ar[ii], wv2[jj], acc[ii][jj + 4]);
                    }
                }
            } else {
#pragma unroll
                for (int ii = 0; ii < 8; ++ii)
#pragma unroll
                    for (int jj = 0; jj < 4; ++jj)
                        acc[ii][jj] = fmaf(ar[ii], wv1[jj], acc[ii][jj]);
            }
        }
        if (kc + 1 < NCHUNK) {
            __syncthreads();
            store_chunk((kc + 1) & 1);
            __syncthreads();
        }
    }

    f4 bv1 = (f4)0.f, bv2 = (f4)0.f;
    if (bias) {
        bv1 = *(const f4*)&bias[c0];
        if (BN == 128) bv2 = *(const f4*)&bias[c0 + 64];
    }
#pragma unroll
    for (int ii = 0; ii < 8; ++ii) {
        int row = row_base + ((ii < 4) ? (r0 + ii) : (64 + r0 + ii - 4));
        if (row < M) {
            f4 o1;
#pragma unroll
            for (int jj = 0; jj < 4; ++jj) {
                float v = acc[ii][jj] + bv1[jj];
                o1[jj] = RELU ? fmaxf(v, 0.f) : v;
            }
            *(f4*)&out[(size_t)row * BN + c0] = o1;
            if (BN == 128) {
                f4 o2;
#pragma unroll
                for (int jj = 0; jj < 4; ++jj) {
                    float v = acc[ii][jj + 4] + bv2[jj];
                    o2[jj] = RELU ? fmaxf(v, 0.f) : v;
                }
                *(f4*)&out[(size_t)row * BN + c0 + 64] = o2;
            }
        }
    }
}

// ---------------- aggregation (CSR gather-sum) ----------------
// one wave per node; lane covers 2 floats of the 128-wide row; index prefetch
__global__ void aggregate_kernel(const float* __restrict__ x, const int* __restrict__ row_off,
                                 const int* __restrict__ csr, float* __restrict__ agg, int N) {
    int gw = (blockIdx.x * 256 + threadIdx.x) >> 6;
    int lane = threadIdx.x & 63;
    if (gw >= N) return;
    int beg = row_off[gw], end = row_off[gw + 1];
    f2 a = (f2)0.f;
    int s = (beg < end) ? csr[beg] : 0;
    for (int j = beg; j < end; ++j) {
        int sn = (j + 1 < end) ? csr[j + 1] : 0;
        a += *(const f2*)&x[(size_t)s * HID + lane * 2];
        s = sn;
    }
    *(f2*)&agg[(size_t)gw * HID + lane * 2] = a;
}

// ---------------- head ----------------
// Wpp[k][c] = head_w[k][c] (c<32) | head_w[128+k][c-32]
__global__ void wpp_kernel(const float* __restrict__ head_w, float* __restrict__ wpp) {
    int idx = blockIdx.x * blockDim.x + threadIdx.x;  // 8192 total
    int k = idx >> 6;
    int c = idx & 63;
    float v = (c < CLASSES) ? head_w[(size_t)k * CLASSES + c]
                            : head_w[(size_t)(HID + k) * CLASSES + (c - CLASSES)];
    wpp[idx] = v;
}

// out[e][c] = pspd[src[e]][c] + pspd[dst[e]][32+c] + head_b[c]
__global__ void edge_out_kernel(const int* __restrict__ src, const int* __restrict__ dst,
                                const float* __restrict__ pspd, const float* __restrict__ head_b,
                                float* __restrict__ out, int E) {
    int idx = blockIdx.x * blockDim.x + threadIdx.x;
    int e = idx >> 3;
    int c4 = (idx & 7) * 4;
    if (e >= E) return;
    int s = src[e], d = dst[e];
    f4 a = *(const f4*)&pspd[(size_t)s * 64 + c4];
    f4 b = *(const f4*)&pspd[(size_t)d * 64 + 32 + c4];
    f4 hb = *(const f4*)&head_b[c4];
    f4 o = a + b + hb;
    *(f4*)&out[(size_t)e * CLASSES + c4] = o;
}

// ---------------- launcher ----------------

extern "C" void kernel_launch(void* const* d_in, const int* in_sizes, int n_in,
                              void* d_out, int out_size, void* d_ws, size_t ws_size,
                              hipStream_t stream) {
    const float* feat   = (const float*)d_in[0];
    const int*   eidx   = (const int*)d_in[1];
    const float* emb_w  = (const float*)d_in[2];
    const float* emb_b  = (const float*)d_in[3];
    const float* rel_w  = (const float*)d_in[4];
    const float* rel_b  = (const float*)d_in[5];
    const float* root_w = (const float*)d_in[6];
    const float* head_w = (const float*)d_in[7];
    const float* head_b = (const float*)d_in[8];
    float* out = (float*)d_out;

    int N = in_sizes[0] / FEAT;
    int E = in_sizes[1] / 2;
    const int* src = eidx;
    const int* dst = eidx + E;

    // workspace layout
    float* xA       = (float*)d_ws;                      // N*HID
    float* xB       = xA + (size_t)N * HID;              // N*HID
    float* agg      = xB + (size_t)N * HID;              // N*HID (reused as pspd[N*64])
    float* wpp      = agg + (size_t)N * HID;             // HID*64
    int*   counts   = (int*)(wpp + HID * 64);            // N
    int*   row_off  = counts + N;                        // N+1
    int*   cursor   = row_off + (N + 1);                 // N
    int*   csr_src  = cursor + N;                        // E
    int*   partials = csr_src + E;                       // ceil(N/256)
    int*   poff     = partials + 256;                    // ceil(N/256)

    int NB = (N + 255) / 256;

    hipMemsetAsync(counts, 0, (size_t)N * sizeof(int), stream);
    count_kernel<<<(E + 255) / 256, 256, 0, stream>>>(dst, counts, E);
    partial_kernel<<<NB, 256, 0, stream>>>(counts, partials, N);
    scan_partials_kernel<<<1, 256, 0, stream>>>(partials, poff, NB);
    scan_final_kernel<<<NB, 256, 0, stream>>>(counts, poff, row_off, cursor, N);
    fill_kernel<<<(E + 255) / 256, 256, 0, stream>>>(src, dst, cursor, csr_src, E);
    wpp_kernel<<<(HID * 64 + 255) / 256, 256, 0, stream>>>(head_w, wpp);

    int grid128 = (N + 127) / 128;
    // embed: x = relu(feat @ emb_w + emb_b)
    gemm_kernel<HID, FEAT, true><<<grid128, 256, 0, stream>>>(
        feat, FEAT, nullptr, 0, emb_w, nullptr, FEAT, emb_b, xA, N);

    const float* xin = xA;
    float* xout = xB;
    for (int l = 0; l < LAYERS; ++l) {
        aggregate_kernel<<<(N * 64 + 255) / 256, 256, 0, stream>>>(xin, row_off, csr_src, agg, N);
        gemm_kernel<HID, 2 * HID, true><<<grid128, 256, 0, stream>>>(
            agg, HID, xin, HID, rel_w + (size_t)l * HID * HID, root_w + (size_t)l * HID * HID,
            HID, rel_b + (size_t)l * HID, xout, N);
        float* tmp = (float*)xin; xin = xout; xout = tmp;
    }

    // pspd = x @ Wpp  (no bias, no relu); reuse agg buffer
    float* pspd = agg;
    gemm_kernel<64, HID, false><<<grid128, 256, 0, stream>>>(
        xin, HID, nullptr, 0, wpp, nullptr, HID, nullptr, pspd, N);

    edge_out_kernel<<<((size_t)E * 8 + 255) / 256, 256, 0, stream>>>(src, dst, pspd, head_b, out, E);
}

// Round 5
// 765.625 us; speedup vs baseline: 3.6167x; 3.6167x over previous
//
#include <hip/hip_runtime.h>
#include <hip/hip_bf16.h>

#define FEAT 256
#define HID 128
#define CLASSES 32
#define LAYERS 3

typedef float f4 __attribute__((ext_vector_type(4)));
typedef float f2 __attribute__((ext_vector_type(2)));

// ---------------- CSR build ----------------

__global__ void count_kernel(const int* __restrict__ dst, int* __restrict__ counts, int E) {
    int e = blockIdx.x * blockDim.x + threadIdx.x;
    if (e < E) atomicAdd(&counts[dst[e]], 1);
}

// per-256-chunk sums
__global__ void partial_kernel(const int* __restrict__ counts, int* __restrict__ partials, int N) {
    int t = threadIdx.x;
    int i = blockIdx.x * 256 + t;
    int v = (i < N) ? counts[i] : 0;
#pragma unroll
    for (int off = 32; off >= 1; off >>= 1) v += __shfl_down(v, off, 64);
    __shared__ int ws[4];
    if ((t & 63) == 0) ws[t >> 6] = v;
    __syncthreads();
    if (t == 0) partials[blockIdx.x] = ws[0] + ws[1] + ws[2] + ws[3];
}

// exclusive scan of partials (NB <= 256), one block
__global__ void scan_partials_kernel(const int* __restrict__ partials, int* __restrict__ poff, int NB) {
    int t = threadIdx.x, lane = t & 63, w = t >> 6;
    int v = (t < NB) ? partials[t] : 0;
    int x = v;
#pragma unroll
    for (int off = 1; off < 64; off <<= 1) {
        int y = __shfl_up(x, off, 64);
        if (lane >= off) x += y;
    }
    __shared__ int ws[4];
    if (lane == 63) ws[w] = x;
    __syncthreads();
    int woff = 0;
    for (int k = 0; k < w; ++k) woff += ws[k];
    if (t < NB) poff[t] = woff + x - v;
}

// final: exclusive scan within chunk + chunk offset
__global__ void scan_final_kernel(const int* __restrict__ counts, const int* __restrict__ poff,
                                  int* __restrict__ row_off, int* __restrict__ cursor, int N) {
    int t = threadIdx.x, lane = t & 63, w = t >> 6;
    int i = blockIdx.x * 256 + t;
    int v = (i < N) ? counts[i] : 0;
    int x = v;
#pragma unroll
    for (int off = 1; off < 64; off <<= 1) {
        int y = __shfl_up(x, off, 64);
        if (lane >= off) x += y;
    }
    __shared__ int ws[4];
    if (lane == 63) ws[w] = x;
    __syncthreads();
    int woff = 0;
    for (int k = 0; k < w; ++k) woff += ws[k];
    int excl = poff[blockIdx.x] + woff + x - v;
    if (i < N) {
        row_off[i] = excl;
        cursor[i] = excl;
        if (i == N - 1) row_off[N] = excl + v;
    }
}

__global__ void fill_kernel(const int* __restrict__ src, const int* __restrict__ dst,
                            int* __restrict__ cursor, int* __restrict__ csr_src, int E) {
    int e = blockIdx.x * blockDim.x + threadIdx.x;
    if (e < E) {
        int pos = atomicAdd(&cursor[dst[e]], 1);
        csr_src[pos] = src[e];
    }
}

// ---------------- tiled fp32 GEMM, 8x8 (or 8x4) per thread ----------------
// out[M x BN] = act( concatK(A0|A1)[M x KTOT] @ concatK(W0;W1)[KTOT x BN] + bias )
// Thread covers rows {r0..r0+3, r0+64..r0+67}, cols {c0..c0+3 (, c0+64..c0+67 if BN==128)}.
// NOTE: no min-waves clamp — the 8x8 tile needs ~160 VGPRs; __launch_bounds__(256,4)
// capped it at 128 and spilled the accumulators to scratch (R4: 2.3 GB HBM/dispatch).
template <int BN, int KTOT, bool RELU>
__global__ __launch_bounds__(256) void gemm_kernel(
    const float* __restrict__ A0, int lda0,
    const float* __restrict__ A1, int lda1,
    const float* __restrict__ W0, const float* __restrict__ W1, int K0,
    const float* __restrict__ bias, float* __restrict__ out, int M) {
    constexpr int BM = 128;
    constexpr int KC = 16;
    constexpr int BMP = BM + 2;            // A pitch (floats); <=2-way bank aliasing
    constexpr int TN = (BN == 128) ? 8 : 4;
    constexpr int WF4 = (KC * BN) / 1024;  // f4 loads per thread for W chunk
    constexpr int AF4 = (KC * BM) / 1024;  // f4 loads per thread for A chunk
    constexpr int NCHUNK = KTOT / KC;

    __shared__ float Wl[2][KC][BN];
    __shared__ float Al[2][KC][BMP];

    int t = threadIdx.x;
    int row_base = blockIdx.x * BM;
    int tc = t & 15;
    int tr = t >> 4;
    int c0 = tc * 4;
    int r0 = tr * 4;

    f4 wreg[WF4], areg[AF4];

    auto load_chunk = [&](int kc) {
        int k0 = kc * KC;
        bool second = (k0 >= K0);
#pragma unroll
        for (int i = 0; i < WF4; ++i) {
            int idx = i * 256 + t;
            int kk = idx / (BN / 4);
            int n4 = idx % (BN / 4);
            int k = k0 + kk;
            const float* p = second ? (W1 + (size_t)(k - K0) * BN + n4 * 4)
                                    : (W0 + (size_t)k * BN + n4 * 4);
            wreg[i] = *(const f4*)p;
        }
#pragma unroll
        for (int i = 0; i < AF4; ++i) {
            int idx = i * 256 + t;
            int row = idx >> 2;
            int kq = idx & 3;
            int row_g = row_base + row;
            if (row_g < M) {
                const float* p = second ? (A1 + (size_t)row_g * lda1 + (k0 - K0) + kq * 4)
                                        : (A0 + (size_t)row_g * lda0 + k0 + kq * 4);
                areg[i] = *(const f4*)p;
            } else {
                areg[i] = (f4)0.f;
            }
        }
    };
    auto store_chunk = [&](int buf) {
#pragma unroll
        for (int i = 0; i < WF4; ++i) {
            int idx = i * 256 + t;
            int kk = idx / (BN / 4);
            int n4 = idx % (BN / 4);
            *(f4*)&Wl[buf][kk][n4 * 4] = wreg[i];
        }
#pragma unroll
        for (int i = 0; i < AF4; ++i) {
            int idx = i * 256 + t;
            int row = idx >> 2;
            int kq = idx & 3;
#pragma unroll
            for (int j = 0; j < 4; ++j) Al[buf][kq * 4 + j][row] = areg[i][j];
        }
    };

    float acc[8][TN] = {{0.f}};
    load_chunk(0);
    store_chunk(0);
    __syncthreads();
    for (int kc = 0; kc < NCHUNK; ++kc) {
        int cur = kc & 1;
        if (kc + 1 < NCHUNK) load_chunk(kc + 1);
#pragma unroll
        for (int k = 0; k < KC; ++k) {
            f4 av1 = *(const f4*)&Al[cur][k][r0];
            f4 av2 = *(const f4*)&Al[cur][k][r0 + 64];
            f4 wv1 = *(const f4*)&Wl[cur][k][c0];
            float ar[8] = {av1[0], av1[1], av1[2], av1[3], av2[0], av2[1], av2[2], av2[3]};
            if (BN == 128) {
                f4 wv2 = *(const f4*)&Wl[cur][k][c0 + 64];
#pragma unroll
                for (int ii = 0; ii < 8; ++ii) {
#pragma unroll
                    for (int jj = 0; jj < 4; ++jj) {
                        acc[ii][jj] = fmaf(ar[ii], wv1[jj], acc[ii][jj]);
                        acc[ii][jj + 4] = fmaf(ar[ii], wv2[jj], acc[ii][jj + 4]);
                    }
                }
            } else {
#pragma unroll
                for (int ii = 0; ii < 8; ++ii)
#pragma unroll
                    for (int jj = 0; jj < 4; ++jj)
                        acc[ii][jj] = fmaf(ar[ii], wv1[jj], acc[ii][jj]);
            }
        }
        if (kc + 1 < NCHUNK) {
            __syncthreads();
            store_chunk((kc + 1) & 1);
            __syncthreads();
        }
    }

    f4 bv1 = (f4)0.f, bv2 = (f4)0.f;
    if (bias) {
        bv1 = *(const f4*)&bias[c0];
        if (BN == 128) bv2 = *(const f4*)&bias[c0 + 64];
    }
#pragma unroll
    for (int ii = 0; ii < 8; ++ii) {
        int row = row_base + ((ii < 4) ? (r0 + ii) : (64 + r0 + ii - 4));
        if (row < M) {
            f4 o1;
#pragma unroll
            for (int jj = 0; jj < 4; ++jj) {
                float v = acc[ii][jj] + bv1[jj];
                o1[jj] = RELU ? fmaxf(v, 0.f) : v;
            }
            *(f4*)&out[(size_t)row * BN + c0] = o1;
            if (BN == 128) {
                f4 o2;
#pragma unroll
                for (int jj = 0; jj < 4; ++jj) {
                    float v = acc[ii][jj + 4] + bv2[jj];
                    o2[jj] = RELU ? fmaxf(v, 0.f) : v;
                }
                *(f4*)&out[(size_t)row * BN + c0 + 64] = o2;
            }
        }
    }
}

// ---------------- aggregation (CSR gather-sum) ----------------
// one wave per node; lane covers 2 floats of the 128-wide row; index prefetch
__global__ void aggregate_kernel(const float* __restrict__ x, const int* __restrict__ row_off,
                                 const int* __restrict__ csr, float* __restrict__ agg, int N) {
    int gw = (blockIdx.x * 256 + threadIdx.x) >> 6;
    int lane = threadIdx.x & 63;
    if (gw >= N) return;
    int beg = row_off[gw], end = row_off[gw + 1];
    f2 a = (f2)0.f;
    int s = (beg < end) ? csr[beg] : 0;
    for (int j = beg; j < end; ++j) {
        int sn = (j + 1 < end) ? csr[j + 1] : 0;
        a += *(const f2*)&x[(size_t)s * HID + lane * 2];
        s = sn;
    }
    *(f2*)&agg[(size_t)gw * HID + lane * 2] = a;
}

// ---------------- head ----------------
// Wpp[k][c] = head_w[k][c] (c<32) | head_w[128+k][c-32]
__global__ void wpp_kernel(const float* __restrict__ head_w, float* __restrict__ wpp) {
    int idx = blockIdx.x * blockDim.x + threadIdx.x;  // 8192 total
    int k = idx >> 6;
    int c = idx & 63;
    float v = (c < CLASSES) ? head_w[(size_t)k * CLASSES + c]
                            : head_w[(size_t)(HID + k) * CLASSES + (c - CLASSES)];
    wpp[idx] = v;
}

// out[e][c] = pspd[src[e]][c] + pspd[dst[e]][32+c] + head_b[c]
__global__ void edge_out_kernel(const int* __restrict__ src, const int* __restrict__ dst,
                                const float* __restrict__ pspd, const float* __restrict__ head_b,
                                float* __restrict__ out, int E) {
    int idx = blockIdx.x * blockDim.x + threadIdx.x;
    int e = idx >> 3;
    int c4 = (idx & 7) * 4;
    if (e >= E) return;
    int s = src[e], d = dst[e];
    f4 a = *(const f4*)&pspd[(size_t)s * 64 + c4];
    f4 b = *(const f4*)&pspd[(size_t)d * 64 + 32 + c4];
    f4 hb = *(const f4*)&head_b[c4];
    f4 o = a + b + hb;
    *(f4*)&out[(size_t)e * CLASSES + c4] = o;
}

// ---------------- launcher ----------------

extern "C" void kernel_launch(void* const* d_in, const int* in_sizes, int n_in,
                              void* d_out, int out_size, void* d_ws, size_t ws_size,
                              hipStream_t stream) {
    const float* feat   = (const float*)d_in[0];
    const int*   eidx   = (const int*)d_in[1];
    const float* emb_w  = (const float*)d_in[2];
    const float* emb_b  = (const float*)d_in[3];
    const float* rel_w  = (const float*)d_in[4];
    const float* rel_b  = (const float*)d_in[5];
    const float* root_w = (const float*)d_in[6];
    const float* head_w = (const float*)d_in[7];
    const float* head_b = (const float*)d_in[8];
    float* out = (float*)d_out;

    int N = in_sizes[0] / FEAT;
    int E = in_sizes[1] / 2;
    const int* src = eidx;
    const int* dst = eidx + E;

    // workspace layout
    float* xA       = (float*)d_ws;                      // N*HID
    float* xB       = xA + (size_t)N * HID;              // N*HID
    float* agg      = xB + (size_t)N * HID;              // N*HID (reused as pspd[N*64])
    float* wpp      = agg + (size_t)N * HID;             // HID*64
    int*   counts   = (int*)(wpp + HID * 64);            // N
    int*   row_off  = counts + N;                        // N+1
    int*   cursor   = row_off + (N + 1);                 // N
    int*   csr_src  = cursor + N;                        // E
    int*   partials = csr_src + E;                       // ceil(N/256)
    int*   poff     = partials + 256;                    // ceil(N/256)

    int NB = (N + 255) / 256;

    hipMemsetAsync(counts, 0, (size_t)N * sizeof(int), stream);
    count_kernel<<<(E + 255) / 256, 256, 0, stream>>>(dst, counts, E);
    partial_kernel<<<NB, 256, 0, stream>>>(counts, partials, N);
    scan_partials_kernel<<<1, 256, 0, stream>>>(partials, poff, NB);
    scan_final_kernel<<<NB, 256, 0, stream>>>(counts, poff, row_off, cursor, N);
    fill_kernel<<<(E + 255) / 256, 256, 0, stream>>>(src, dst, cursor, csr_src, E);
    wpp_kernel<<<(HID * 64 + 255) / 256, 256, 0, stream>>>(head_w, wpp);

    int grid128 = (N + 127) / 128;
    // embed: x = relu(feat @ emb_w + emb_b)
    gemm_kernel<HID, FEAT, true><<<grid128, 256, 0, stream>>>(
        feat, FEAT, nullptr, 0, emb_w, nullptr, FEAT, emb_b, xA, N);

    const float* xin = xA;
    float* xout = xB;
    for (int l = 0; l < LAYERS; ++l) {
        aggregate_kernel<<<(N * 64 + 255) / 256, 256, 0, stream>>>(xin, row_off, csr_src, agg, N);
        gemm_kernel<HID, 2 * HID, true><<<grid128, 256, 0, stream>>>(
            agg, HID, xin, HID, rel_w + (size_t)l * HID * HID, root_w + (size_t)l * HID * HID,
            HID, rel_b + (size_t)l * HID, xout, N);
        float* tmp = (float*)xin; xin = xout; xout = tmp;
    }

    // pspd = x @ Wpp  (no bias, no relu); reuse agg buffer
    float* pspd = agg;
    gemm_kernel<64, HID, false><<<grid128, 256, 0, stream>>>(
        xin, HID, nullptr, 0, wpp, nullptr, HID, nullptr, pspd, N);

    edge_out_kernel<<<((size_t)E * 8 + 255) / 256, 256, 0, stream>>>(src, dst, pspd, head_b, out, E);
}

// Round 6
// 608.998 us; speedup vs baseline: 4.5469x; 1.2572x over previous
//
#include <hip/hip_runtime.h>
#include <hip/hip_bf16.h>

#define FEAT 256
#define HID 128
#define CLASSES 32
#define LAYERS 3

typedef float f4 __attribute__((ext_vector_type(4)));
typedef float f2 __attribute__((ext_vector_type(2)));
typedef __attribute__((ext_vector_type(8))) short short8;
typedef __attribute__((ext_vector_type(4))) float f32x4;

// split fp32 into bf16 hi + bf16 lo (RNE); v - hf is exact in fp32
__device__ __forceinline__ void split_bf16(float v, short& hi, short& lo) {
    unsigned u = __float_as_uint(v);
    unsigned r = (u + 0x7FFF + ((u >> 16) & 1)) >> 16;
    hi = (short)r;
    float hf = __uint_as_float(r << 16);
    float d = v - hf;
    unsigned u2 = __float_as_uint(d);
    unsigned r2 = (u2 + 0x7FFF + ((u2 >> 16) & 1)) >> 16;
    lo = (short)r2;
}

// ---------------- CSR build ----------------

__global__ void count_kernel(const int* __restrict__ dst, int* __restrict__ counts, int E) {
    int e = blockIdx.x * blockDim.x + threadIdx.x;
    if (e < E) atomicAdd(&counts[dst[e]], 1);
}

__global__ void partial_kernel(const int* __restrict__ counts, int* __restrict__ partials, int N) {
    int t = threadIdx.x;
    int i = blockIdx.x * 256 + t;
    int v = (i < N) ? counts[i] : 0;
#pragma unroll
    for (int off = 32; off >= 1; off >>= 1) v += __shfl_down(v, off, 64);
    __shared__ int ws[4];
    if ((t & 63) == 0) ws[t >> 6] = v;
    __syncthreads();
    if (t == 0) partials[blockIdx.x] = ws[0] + ws[1] + ws[2] + ws[3];
}

__global__ void scan_partials_kernel(const int* __restrict__ partials, int* __restrict__ poff, int NB) {
    int t = threadIdx.x, lane = t & 63, w = t >> 6;
    int v = (t < NB) ? partials[t] : 0;
    int x = v;
#pragma unroll
    for (int off = 1; off < 64; off <<= 1) {
        int y = __shfl_up(x, off, 64);
        if (lane >= off) x += y;
    }
    __shared__ int ws[4];
    if (lane == 63) ws[w] = x;
    __syncthreads();
    int woff = 0;
    for (int k = 0; k < w; ++k) woff += ws[k];
    if (t < NB) poff[t] = woff + x - v;
}

__global__ void scan_final_kernel(const int* __restrict__ counts, const int* __restrict__ poff,
                                  int* __restrict__ row_off, int* __restrict__ cursor, int N) {
    int t = threadIdx.x, lane = t & 63, w = t >> 6;
    int i = blockIdx.x * 256 + t;
    int v = (i < N) ? counts[i] : 0;
    int x = v;
#pragma unroll
    for (int off = 1; off < 64; off <<= 1) {
        int y = __shfl_up(x, off, 64);
        if (lane >= off) x += y;
    }
    __shared__ int ws[4];
    if (lane == 63) ws[w] = x;
    __syncthreads();
    int woff = 0;
    for (int k = 0; k < w; ++k) woff += ws[k];
    int excl = poff[blockIdx.x] + woff + x - v;
    if (i < N) {
        row_off[i] = excl;
        cursor[i] = excl;
        if (i == N - 1) row_off[N] = excl + v;
    }
}

__global__ void fill_kernel(const int* __restrict__ src, const int* __restrict__ dst,
                            int* __restrict__ cursor, int* __restrict__ csr_src, int E) {
    int e = blockIdx.x * blockDim.x + threadIdx.x;
    if (e < E) {
        int pos = atomicAdd(&cursor[dst[e]], 1);
        csr_src[pos] = src[e];
    }
}

// ---------------- weight prep: transposed bf16 hi/lo tables ----------------
// we:  [n=128][k=256]  from emb_w[k][n]
// wl:  3 x [n=128][k=256]; k<128 -> rel_w[l][k][n], k>=128 -> root_w[l][k-128][n]
// wp:  [c=64][k=128]; c<32 -> head_w[k][c], else head_w[128+k][c-32]
__global__ void prep_emb_kernel(const float* __restrict__ emb_w,
                                unsigned short* __restrict__ hi, unsigned short* __restrict__ lo) {
    int idx = blockIdx.x * 256 + threadIdx.x;  // 128*256
    if (idx >= 128 * 256) return;
    int n = idx >> 8, k = idx & 255;
    short h, l;
    split_bf16(emb_w[k * 128 + n], h, l);
    hi[n * 256 + k] = (unsigned short)h;
    lo[n * 256 + k] = (unsigned short)l;
}

__global__ void prep_layer_kernel(const float* __restrict__ rel_w, const float* __restrict__ root_w,
                                  unsigned short* __restrict__ hi, unsigned short* __restrict__ lo) {
    int idx = blockIdx.x * 256 + threadIdx.x;  // 3*128*256
    if (idx >= 3 * 128 * 256) return;
    int l = idx >> 15;
    int r = idx & 32767;
    int n = r >> 8, k = r & 255;
    float w = (k < 128) ? rel_w[l * 16384 + k * 128 + n] : root_w[l * 16384 + (k - 128) * 128 + n];
    short h, lw;
    split_bf16(w, h, lw);
    hi[idx] = (unsigned short)h;
    lo[idx] = (unsigned short)lw;
}

__global__ void prep_head_kernel(const float* __restrict__ head_w,
                                 unsigned short* __restrict__ hi, unsigned short* __restrict__ lo) {
    int idx = blockIdx.x * 256 + threadIdx.x;  // 64*128
    if (idx >= 64 * 128) return;
    int c = idx >> 7, k = idx & 127;
    float w = (c < 32) ? head_w[k * 32 + c] : head_w[(128 + k) * 32 + (c - 32)];
    short h, l;
    split_bf16(w, h, l);
    hi[c * 128 + k] = (unsigned short)h;
    lo[c * 128 + k] = (unsigned short)l;
}

// ---------------- MFMA split-bf16 GEMM (LDS-free, barrier-free) ----------------
// out[M x NCOL] = act( concatK(A0|A1)[M x KTOT] @ W[KTOT x NCOL] + bias )
// W given pre-transposed bf16 hi/lo: Whi/Wlo[n][k] (n-major, stride KTOT).
// Block = 256 threads = 4 waves; wave w owns rows [blk*128 + w*32, +32) x all NCOL cols.
template <int NCOL, int KTOT, bool RELU>
__global__ __launch_bounds__(256) void gemm_mfma(
    const float* __restrict__ A0, int lda0,
    const float* __restrict__ A1, int lda1, int K0,
    const unsigned short* __restrict__ Whi, const unsigned short* __restrict__ Wlo,
    const float* __restrict__ bias, float* __restrict__ out, int M) {
    constexpr int NCHUNK = KTOT / 32;
    constexpr int NCT = NCOL / 16;  // 8 (NCOL=128) or 4 (NCOL=64)
    int wv = threadIdx.x >> 6;
    int lane = threadIdx.x & 63;
    int m16 = lane & 15;
    int quad = lane >> 4;
    int rowbase = blockIdx.x * 128 + wv * 32;

    f32x4 acc[2][NCT] = {};
    float bcol[NCT];
#pragma unroll
    for (int ct = 0; ct < NCT; ++ct) bcol[ct] = bias ? bias[ct * 16 + m16] : 0.f;

    for (int kc = 0; kc < NCHUNK; ++kc) {
        bool second = (kc * 32 >= K0);
        const float* Ab = second ? A1 : A0;
        int lda = second ? lda1 : lda0;
        int kofs = kc * 32 - (second ? K0 : 0);

        // A fragments: lane m16 = row-in-tile, quad picks k-group of 8; convert in-register
        short8 Ah[2], Al[2];
#pragma unroll
        for (int rt = 0; rt < 2; ++rt) {
            int row = rowbase + rt * 16 + m16;
            row = (row < M) ? row : (M - 1);  // clamp reads; stores guarded below
            const float* ap = Ab + (size_t)row * lda + kofs + quad * 8;
            f4 a0 = *(const f4*)ap;
            f4 a1 = *(const f4*)(ap + 4);
            float av[8] = {a0[0], a0[1], a0[2], a0[3], a1[0], a1[1], a1[2], a1[3]};
#pragma unroll
            for (int j = 0; j < 8; ++j) {
                short h, l;
                split_bf16(av[j], h, l);
                Ah[rt][j] = h;
                Al[rt][j] = l;
            }
        }

        // B fragments direct from global (L2-resident weight tables), 3-pass MFMA
#pragma unroll
        for (int ct = 0; ct < NCT; ++ct) {
            size_t wb = (size_t)(ct * 16 + m16) * KTOT + kc * 32 + quad * 8;
            short8 Bh = *(const short8*)(Whi + wb);
            short8 Bl = *(const short8*)(Wlo + wb);
#pragma unroll
            for (int rt = 0; rt < 2; ++rt) {
                acc[rt][ct] = __builtin_amdgcn_mfma_f32_16x16x32_bf16(Ah[rt], Bh, acc[rt][ct], 0, 0, 0);
                acc[rt][ct] = __builtin_amdgcn_mfma_f32_16x16x32_bf16(Al[rt], Bh, acc[rt][ct], 0, 0, 0);
                acc[rt][ct] = __builtin_amdgcn_mfma_f32_16x16x32_bf16(Ah[rt], Bl, acc[rt][ct], 0, 0, 0);
            }
        }
    }

    // epilogue: C/D layout col = lane&15, row = quad*4 + reg
#pragma unroll
    for (int rt = 0; rt < 2; ++rt) {
#pragma unroll
        for (int r = 0; r < 4; ++r) {
            int row = rowbase + rt * 16 + quad * 4 + r;
            if (row < M) {
#pragma unroll
                for (int ct = 0; ct < NCT; ++ct) {
                    float v = acc[rt][ct][r] + bcol[ct];
                    out[(size_t)row * NCOL + ct * 16 + m16] = RELU ? fmaxf(v, 0.f) : v;
                }
            }
        }
    }
}

// ---------------- aggregation (CSR gather-sum) ----------------
__global__ void aggregate_kernel(const float* __restrict__ x, const int* __restrict__ row_off,
                                 const int* __restrict__ csr, float* __restrict__ agg, int N) {
    int gw = (blockIdx.x * 256 + threadIdx.x) >> 6;
    int lane = threadIdx.x & 63;
    if (gw >= N) return;
    int beg = row_off[gw], end = row_off[gw + 1];
    f2 a = (f2)0.f;
    int s = (beg < end) ? csr[beg] : 0;
    for (int j = beg; j < end; ++j) {
        int sn = (j + 1 < end) ? csr[j + 1] : 0;
        a += *(const f2*)&x[(size_t)s * HID + lane * 2];
        s = sn;
    }
    *(f2*)&agg[(size_t)gw * HID + lane * 2] = a;
}

// ---------------- edge head ----------------
// out[e][c] = pspd[src[e]][c] + pspd[dst[e]][32+c] + head_b[c]
__global__ void edge_out_kernel(const int* __restrict__ src, const int* __restrict__ dst,
                                const float* __restrict__ pspd, const float* __restrict__ head_b,
                                float* __restrict__ out, int E) {
    int idx = blockIdx.x * blockDim.x + threadIdx.x;
    int e = idx >> 3;
    int c4 = (idx & 7) * 4;
    if (e >= E) return;
    int s = src[e], d = dst[e];
    f4 a = *(const f4*)&pspd[(size_t)s * 64 + c4];
    f4 b = *(const f4*)&pspd[(size_t)d * 64 + 32 + c4];
    f4 hb = *(const f4*)&head_b[c4];
    f4 o = a + b + hb;
    *(f4*)&out[(size_t)e * CLASSES + c4] = o;
}

// ---------------- launcher ----------------

extern "C" void kernel_launch(void* const* d_in, const int* in_sizes, int n_in,
                              void* d_out, int out_size, void* d_ws, size_t ws_size,
                              hipStream_t stream) {
    const float* feat   = (const float*)d_in[0];
    const int*   eidx   = (const int*)d_in[1];
    const float* emb_w  = (const float*)d_in[2];
    const float* emb_b  = (const float*)d_in[3];
    const float* rel_w  = (const float*)d_in[4];
    const float* rel_b  = (const float*)d_in[5];
    const float* root_w = (const float*)d_in[6];
    const float* head_w = (const float*)d_in[7];
    const float* head_b = (const float*)d_in[8];
    float* out = (float*)d_out;

    int N = in_sizes[0] / FEAT;
    int E = in_sizes[1] / 2;
    const int* src = eidx;
    const int* dst = eidx + E;

    // workspace layout: floats, then ints, then ushort weight tables (16B-aligned)
    float* xA  = (float*)d_ws;               // N*128
    float* xB  = xA + (size_t)N * HID;       // N*128
    float* agg = xB + (size_t)N * HID;       // N*128 (pspd reuses as N*64)
    int* counts   = (int*)(agg + (size_t)N * HID);  // N
    int* row_off  = counts + N;                     // N+1
    int* cursor   = row_off + (N + 1);              // N
    int* csr_src  = cursor + N;                     // E
    int* partials = csr_src + E;                    // 256
    int* poff     = partials + 256;                 // 256
    int* iend     = poff + 256;
    // pad int region to 16B boundary
    size_t ioff = (size_t)(iend - (int*)d_ws);
    ioff = (ioff + 3) & ~(size_t)3;
    unsigned short* we_hi = (unsigned short*)((int*)d_ws + ioff);
    unsigned short* we_lo = we_hi + 128 * 256;
    unsigned short* wl_hi = we_lo + 128 * 256;      // 3*128*256
    unsigned short* wl_lo = wl_hi + 3 * 128 * 256;  // 3*128*256
    unsigned short* wp_hi = wl_lo + 3 * 128 * 256;  // 64*128
    unsigned short* wp_lo = wp_hi + 64 * 128;       // 64*128

    int NB = (N + 255) / 256;

    hipMemsetAsync(counts, 0, (size_t)N * sizeof(int), stream);
    count_kernel<<<(E + 255) / 256, 256, 0, stream>>>(dst, counts, E);
    partial_kernel<<<NB, 256, 0, stream>>>(counts, partials, N);
    scan_partials_kernel<<<1, 256, 0, stream>>>(partials, poff, NB);
    scan_final_kernel<<<NB, 256, 0, stream>>>(counts, poff, row_off, cursor, N);
    fill_kernel<<<(E + 255) / 256, 256, 0, stream>>>(src, dst, cursor, csr_src, E);

    prep_emb_kernel<<<(128 * 256 + 255) / 256, 256, 0, stream>>>(emb_w, we_hi, we_lo);
    prep_layer_kernel<<<(3 * 128 * 256 + 255) / 256, 256, 0, stream>>>(rel_w, root_w, wl_hi, wl_lo);
    prep_head_kernel<<<(64 * 128 + 255) / 256, 256, 0, stream>>>(head_w, wp_hi, wp_lo);

    int grid = (N + 127) / 128;
    // embed: x = relu(feat @ emb_w + emb_b)
    gemm_mfma<HID, FEAT, true><<<grid, 256, 0, stream>>>(
        feat, FEAT, nullptr, 0, FEAT, we_hi, we_lo, emb_b, xA, N);

    const float* xin = xA;
    float* xout = xB;
    for (int l = 0; l < LAYERS; ++l) {
        aggregate_kernel<<<(N * 64 + 255) / 256, 256, 0, stream>>>(xin, row_off, csr_src, agg, N);
        gemm_mfma<HID, 2 * HID, true><<<grid, 256, 0, stream>>>(
            agg, HID, xin, HID, HID,
            wl_hi + (size_t)l * 128 * 256, wl_lo + (size_t)l * 128 * 256,
            rel_b + (size_t)l * HID, xout, N);
        float* tmp = (float*)xin; xin = xout; xout = tmp;
    }

    // pspd = x @ Wpp (no bias/relu); reuse agg
    float* pspd = agg;
    gemm_mfma<64, HID, false><<<grid, 256, 0, stream>>>(
        xin, HID, nullptr, 0, HID, wp_hi, wp_lo, nullptr, pspd, N);

    edge_out_kernel<<<((size_t)E * 8 + 255) / 256, 256, 0, stream>>>(src, dst, pspd, head_b, out, E);
}